// Round 7
// baseline (116.813 us; speedup 1.0000x reference)
//
#include <hip/hip_runtime.h>
#include <cstdint>
#include <cstddef>

#define BB 16
#define NN 4096
#define CC 80
#define MAXD 100
#define CONF_T 0.5f
#define PER_B (MAXD * 4 + MAXD * CC)   // 8400 output elems per batch
#define NWORDS 64                      // 4096/64 bitmap words (fallback)
#define FBCAP 2048                     // fallback kernel's capacity
#define SEGSZ 2048
#define NMSB   BB                      // 16 NMS blocks (one per batch)
#define NPROD  240                     // producer blocks; NMSB+NPROD = 256 = #CUs
#define RPB    274                     // rows per producer block (240*274 >= 65536)

// fl32(inter/uni) > 0.5  <=>  inter > uni*(0.5+2^-25), evaluated EXACTLY in
// fp64 (24-bit x 25-bit mantissa product = 49 bits < 53). Bit-identical to
// the reference's IEEE divide + compare. (verified passing rounds 9)
#define IOUC 0x1.000001p-1

// ---- workspace layout ----
#define WS_KEYS   0x000000             // [B*N] u64
#define WS_CNT    0x100000             // [B] int readiness counters (rows done)
#define WS_NEED   0x200000             // 2 MB

// ---------------------------------------------------------------------------
// K1 standalone softmax (FALLBACK PATH ONLY — fused path has it inline).
// 8 LANES per row, all-register. Verbatim verified round-2 math.
// ---------------------------------------------------------------------------
__global__ __launch_bounds__(256) void k_softmax(const float* __restrict__ cls_in,
                                                 float* __restrict__ probs,
                                                 uint64_t* __restrict__ keys) {
#pragma clang fp contract(off)
    int slot = blockIdx.x * 256 + threadIdx.x;   // 8 slots per row
    int row  = slot >> 3;                        // [0, B*N)
    int j    = slot & 7;
    const float* rp = cls_in + (size_t)row * CC + j;

    float e[10];
    float m = -3.402823466e+38f;
    #pragma unroll
    for (int k = 0; k < 10; ++k) {
        float y = rp[8 * k] * 10.0f;
        float z = y * y;
        e[k] = z;
        m = fmaxf(m, z);
    }
    m = fmaxf(m, __shfl_xor(m, 1));
    m = fmaxf(m, __shfl_xor(m, 2));
    m = fmaxf(m, __shfl_xor(m, 4));

    #pragma unroll
    for (int k = 0; k < 10; ++k) e[k] = expf(e[k] - m);

    float acc = e[0];
    #pragma unroll
    for (int k = 1; k < 10; ++k) acc += e[k];
    acc = acc + __shfl_xor(acc, 1);
    acc = acc + __shfl_xor(acc, 2);
    acc = acc + __shfl_xor(acc, 4);

    float score = 1.0f / acc;
    float* pp = probs + (size_t)row * CC + j;
    #pragma unroll
    for (int k = 0; k < 10; ++k) pp[8 * k] = e[k] * score;

    if (j == 0) {
        unsigned n = (unsigned)(row & (NN - 1));
        keys[row] = ((uint64_t)__float_as_uint(score) << 32)
                  | (uint64_t)(0xFFFFFFFFu - n);
    }
}

// ---------------------------------------------------------------------------
// K_FUSED: producer/consumer single kernel, grid = EXACTLY 256 blocks so all
// blocks are resident from t=0 (1 block/CU at 134 KB LDS; 256 CUs). This is
// the r5 structure with the occupancy bug fixed (r5: 528 blocks -> 2 rounds).
//   blocks [NMSB, 256): producers — RPB=274 softmax rows each (3 passes of
//     128 rows, verbatim round-2 math). After all stores: __syncthreads
//     (drains vmem) -> threadfence -> release atomicAdd of ROW COUNT into
//     cnt[batch] (a block's row range spans at most 2 batches).
//   blocks [0, NMSB): per-batch NMS. Build RAW-order corner LDS from boxes
//     (input — overlaps producers), spin until cnt[b]==NN rows (acquire),
//     then partition + rank-sort + block-sequential greedy NMS + fused
//     gather — all verbatim from the PASSING r5 kernel.
// Deadlock-free by capacity: 256 blocks <= 256 CUs, all resident.
// ---------------------------------------------------------------------------
__global__ __launch_bounds__(1024) void k_fused(const float* __restrict__ boxes,
                                                const float* __restrict__ cls_in,
                                                float* __restrict__ probs,
                                                uint64_t* __restrict__ keys,
                                                int* cnt,
                                                float* __restrict__ out_box,
                                                float* __restrict__ out_cls) {
#pragma clang fp contract(off)
    __shared__ float ry1[NN], rx1[NN], ry2[NN], rx2[NN], rar[NN];   // 80 KB raw-order
    __shared__ int og[NN];                                          // 16 KB sorted->raw
    __shared__ uint64_t bbuf[NN];                                   // 32 KB sort keys
    __shared__ uint64_t kill[64];
    __shared__ uint64_t persup[16];
    __shared__ float ky1[MAXD], kx1[MAXD], ky2[MAXD], kx2[MAXD], kar[MAXD];
    __shared__ int kpos[MAXD];                                      // raw indices of keeps
    __shared__ int wsumA[16], wsumB[16];
    __shared__ int kept_s, done_s;

    const int tid = threadIdx.x, lane = tid & 63, wv = tid >> 6;
    const int blk = blockIdx.x;

    if (blk >= NMSB) {
        // ---------------- producer role: softmax of RPB rows ----------------
        int p = blk - NMSB;                       // 0..NPROD-1
        int lo = p * RPB;
        int hi = lo + RPB; if (hi > BB * NN) hi = BB * NN;
        int j = tid & 7;
        for (int slot = (tid >> 3); lo + slot < hi; slot += 128) {
            int row = lo + slot;
            const float* rp = cls_in + (size_t)row * CC + j;

            float e[10];
            float m = -3.402823466e+38f;
            #pragma unroll
            for (int k = 0; k < 10; ++k) {
                float y = rp[8 * k] * 10.0f;
                float z = y * y;
                e[k] = z;
                m = fmaxf(m, z);
            }
            m = fmaxf(m, __shfl_xor(m, 1));
            m = fmaxf(m, __shfl_xor(m, 2));
            m = fmaxf(m, __shfl_xor(m, 4));
            #pragma unroll
            for (int k = 0; k < 10; ++k) e[k] = expf(e[k] - m);
            float acc = e[0];
            #pragma unroll
            for (int k = 1; k < 10; ++k) acc += e[k];
            acc = acc + __shfl_xor(acc, 1);
            acc = acc + __shfl_xor(acc, 2);
            acc = acc + __shfl_xor(acc, 4);
            float score = 1.0f / acc;
            float* pp = probs + (size_t)row * CC + j;
            #pragma unroll
            for (int k = 0; k < 10; ++k) pp[8 * k] = e[k] * score;
            if (j == 0) {
                unsigned n = (unsigned)(row & (NN - 1));
                keys[row] = ((uint64_t)__float_as_uint(score) << 32)
                          | (uint64_t)(0xFFFFFFFFu - n);
            }
        }
        __syncthreads();   // compiler drains vmcnt before s_barrier: stores issued
        if (tid == 0 && lo < hi) {
            __threadfence();
            int b0 = lo >> 12, b1 = (hi - 1) >> 12;    // at most 2 batches
            for (int bb2 = b0; bb2 <= b1; ++bb2) {
                int s = bb2 << 12, e2 = (bb2 + 1) << 12;
                int c0 = lo > s ? lo : s;
                int c1 = hi < e2 ? hi : e2;
                if (c1 > c0)
                    __hip_atomic_fetch_add(&cnt[bb2], c1 - c0, __ATOMIC_RELEASE,
                                           __HIP_MEMORY_SCOPE_AGENT);
            }
        }
        return;
    }

    // ---------------- NMS role (block b = batch b) — verbatim r5 ----------------
    const int b = blk;
    const float* bxp = boxes + (size_t)b * NN * 4;
    const uint64_t* kb = keys + (size_t)b * NN;

    // raw-order corner build from input boxes — overlaps producer execution
    for (int i = tid; i < NN; i += 1024) {
        float4 bv = ((const float4*)bxp)[i];
        float y1 = fminf(bv.x, bv.z), y2 = fmaxf(bv.x, bv.z);
        float x1 = fminf(bv.y, bv.w), x2 = fmaxf(bv.y, bv.w);
        ry1[i] = y1; rx1[i] = x1; ry2[i] = y2; rx2[i] = x2;
        rar[i] = (y2 - y1) * (x2 - x1);
    }
    // wait for this batch's producers (keys + probs complete: NN rows)
    if (tid == 0) {
        while (__hip_atomic_load(&cnt[b], __ATOMIC_ACQUIRE,
                                 __HIP_MEMORY_SCOPE_AGENT) < NN)
            __builtin_amdgcn_s_sleep(8);
        __threadfence();
    }
    __syncthreads();

    // ---- partition (verbatim) ----
    uint64_t myk[4]; bool fa[4], fb[4];
    int asum = 0, bsum = 0;
    for (int k = 0; k < 4; ++k) {
        uint64_t key = kb[4 * tid + k]; myk[k] = key;
        unsigned hi = (unsigned)(key >> 32);
        fa[k] = (hi == 0x3F800000u);
        fb[k] = (__uint_as_float(hi) > CONF_T) && !fa[k];
        asum += fa[k] ? 1 : 0; bsum += fb[k] ? 1 : 0;
    }
    int ia = asum, ib = bsum;                       // wave-inclusive scans
    for (int off = 1; off < 64; off <<= 1) {
        int va = __shfl_up(ia, off), vb = __shfl_up(ib, off);
        if (lane >= off) { ia += va; ib += vb; }
    }
    if (lane == 63) { wsumA[wv] = ia; wsumB[wv] = ib; }
    __syncthreads();
    int baseA = 0, baseB = 0, cntA = 0, cntB = 0;
    for (int w2 = 0; w2 < 16; ++w2) {
        if (w2 < wv) { baseA += wsumA[w2]; baseB += wsumB[w2]; }
        cntA += wsumA[w2]; cntB += wsumB[w2];
    }
    int pA = baseA + (ia - asum);
    int pB = baseB + (ib - bsum);
    for (int k = 0; k < 4; ++k) {
        if (fa[k]) og[pA++] = 4 * tid + k;          // stable: idx order
        if (fb[k]) bbuf[pB++] = myk[k];             // pB < cntB <= 4096 always
    }
    __syncthreads();

    // ---- rank sort of B (descending, keys unique): one barrier ----
    for (int i = tid; i < cntB; i += 1024) {
        uint64_t ki = bbuf[i];
        int rank = 0;
        for (int j = 0; j < cntB; ++j) rank += (bbuf[j] > ki) ? 1 : 0;
        og[cntA + rank] = (int)(0xFFFFFFFFu - (unsigned)(ki & 0xFFFFFFFFull));
    }
    int nl = cntA + cntB; if (nl > NN) nl = NN;
    if (tid == 0) { kept_s = 0; done_s = 0; }

    // ---- block-sequential greedy over 64-wide g-blocks (raw-order corners,
    //      og[] indirection; verbatim r5/r4 structure) ----
    int ng = (nl + 63) >> 6;
    for (int g = 0; g < ng; ++g) {
        __syncthreads();                           // S0: publish kept/done (+og/init)
        if (done_s) break;                         // uniform
        int kt = kept_s;                           // uniform; < MAXD here (else done)
        int i = g * 64 + lane;
        bool v = i < nl;
        int sog = v ? og[i] : 0;                   // raw index of sorted-pos i
        float y1 = ry1[sog], x1 = rx1[sog], y2 = ry2[sog], x2 = rx2[sog], ar = rar[sog];

        // -- phase 1: pre-filter vs keeps, strided across waves --
        bool killed = false;
        for (int q = wv; q < kt; q += 16) {        // wave-uniform broadcast reads
            float qy1 = ky1[q], qx1 = kx1[q], qy2 = ky2[q], qx2 = kx2[q], qar = kar[q];
            float ih = fmaxf(0.f, fminf(y2, qy2) - fmaxf(y1, qy1));
            float iw = fmaxf(0.f, fminf(x2, qx2) - fmaxf(x1, qx1));
            float inter = ih * iw;
            float uni = (ar + qar) - inter;
            killed = killed || (inter > 0.f && (double)inter > (double)uni * IOUC);
        }
        uint64_t pw = __ballot((!v) || killed);
        if (lane == 0) persup[wv] = pw;
        __syncthreads();                           // S1: persup ready
        uint64_t sup0 = 0;
        #pragma unroll
        for (int w2 = 0; w2 < 16; ++w2) sup0 |= persup[w2];
        if (sup0 == ~0ull) continue;               // uniform: block fully dead

        // -- phase 2: 64x64 kill matrix, 4 row-ballots per wave --
        #pragma unroll
        for (int r = 0; r < 4; ++r) {
            int t = wv + 16 * r;
            int it = g * 64 + t;
            bool tv = it < nl;
            int tog = tv ? og[it] : 0;             // wave-uniform broadcast
            float ty1 = ry1[tog], tx1 = rx1[tog], ty2 = ry2[tog], tx2 = rx2[tog], tar = rar[tog];
            float ih = fmaxf(0.f, fminf(ty2, y2) - fmaxf(ty1, y1));
            float iw = fmaxf(0.f, fminf(tx2, x2) - fmaxf(tx1, x1));
            float inter = ih * iw;
            float uni = (tar + ar) - inter;
            bool s = tv && v && (inter > 0.f) && ((double)inter > (double)uni * IOUC);
            uint64_t w = __ballot(s);
            if (lane == 0) kill[t] = w;
        }
        __syncthreads();                           // S2: kill ready

        // -- phase 3: exact greedy replay (wave0), 8x8 register prefetch --
        if (wv == 0) {
            uint64_t sup = sup0, keptm = 0;
            #pragma unroll
            for (int c8 = 0; c8 < 8; ++c8) {
                uint64_t kk[8];
                #pragma unroll
                for (int u = 0; u < 8; ++u) kk[u] = kill[c8 * 8 + u];  // independent loads
                #pragma unroll
                for (int u = 0; u < 8; ++u) {
                    int t = c8 * 8 + u;
                    if (!((sup >> t) & 1ull)) { keptm |= 1ull << t; sup |= kk[u]; }
                }
            }
            int k0 = kept_s;
            if ((keptm >> lane) & 1ull) {
                int pos = k0 + __popcll(keptm & ((1ull << lane) - 1ull));
                if (pos < MAXD) {
                    kpos[pos] = sog;               // raw index
                    ky1[pos] = y1; kx1[pos] = x1;
                    ky2[pos] = y2; kx2[pos] = x2; kar[pos] = ar;
                }
            }
            if (lane == 0) {
                int k1 = k0 + __popcll(keptm);
                kept_s = k1;
                done_s = (k1 >= MAXD) ? 1 : 0;
            }
        }
        // next iteration's S0 (or the final barrier) publishes wave0's writes
    }
    __syncthreads();                               // publish kept_s/kpos

    // ---- fused output gather (exact k_gather semantics; kpos = raw idx) ----
    int ktf = kept_s; if (ktf > MAXD) ktf = MAXD;
    float* ob = out_box + (size_t)b * MAXD * 4;
    float* oc = out_cls + (size_t)b * MAXD * CC;
    const float* pb = probs + (size_t)b * NN * CC;
    for (int r = tid; r < MAXD * 4; r += 1024) {
        int t = r >> 2, e2 = r & 3;
        float val = 0.0f;
        if (t < ktf) { int idx = kpos[t]; val = bxp[(size_t)idx * 4 + e2]; }
        ob[r] = val;
    }
    for (int q = tid; q < MAXD * CC; q += 1024) {
        int t = q / CC, c = q - t * CC;
        float val = 0.0f;
        if (t < ktf) { int idx = kpos[t]; val = pb[(size_t)idx * CC + c]; }
        oc[q] = val;
    }
}

// ---------------------------------------------------------------------------
// K4: wide parallel gather (fallback path only).
// ---------------------------------------------------------------------------
__global__ __launch_bounds__(256) void k_gather(const float* __restrict__ boxes,
                                                const float* __restrict__ probs,
                                                const int* __restrict__ kidx,
                                                const int* __restrict__ cnt,
                                                float* __restrict__ out_box,
                                                float* __restrict__ out_cls) {
    int u = blockIdx.x * 256 + threadIdx.x;
    if (u >= BB * PER_B) return;
    int b = u / PER_B;
    int r = u - b * PER_B;
    int count = cnt[b];
    float val = 0.0f;
    if (r < MAXD * 4) {
        int t = r >> 2, e = r & 3;
        if (t < count) {
            int idx = kidx[b * MAXD + t];
            val = boxes[((size_t)b * NN + idx) * 4 + e];
        }
        out_box[(size_t)b * MAXD * 4 + r] = val;
    } else {
        int q = r - MAXD * 4;
        int t = q / CC, c = q - t * CC;
        if (t < count) {
            int idx = kidx[b * MAXD + t];
            val = probs[((size_t)b * NN + idx) * CC + c];
        }
        out_cls[(size_t)b * MAXD * CC + q] = val;
    }
}

// ---------------------------------------------------------------------------
// FALLBACK (ws too small): round-4 fused k_nms — verified passing.
// ---------------------------------------------------------------------------
__global__ __launch_bounds__(1024) void k_nms_fb(uint64_t* keys,
                                                 const float* __restrict__ boxes,
                                                 int* __restrict__ kidx_out,
                                                 int* __restrict__ cnt_out) {
#pragma clang fp contract(off)
    __shared__ float sy1[SEGSZ], sx1[SEGSZ], sy2[SEGSZ], sx2[SEGSZ];
    __shared__ int   soidx[SEGSZ];
    __shared__ uint64_t bbuf[FBCAP];
    __shared__ uint64_t sup[NWORDS];
    __shared__ float ky1[MAXD], kx1[MAXD], ky2[MAXD], kx2[MAXD], kar[MAXD];
    __shared__ int   keptidx[MAXD];
    __shared__ int   wsumA[16], wsumB[16];
    __shared__ int   keptcnt_s, ctrl_s, seg_s;

    const int tid = threadIdx.x, lane = tid & 63, wv = tid >> 6;
    const int b = blockIdx.x;
    const uint64_t* kb = keys + (size_t)b * NN;
    const float* bxp = boxes + (size_t)b * NN * 4;
    int* og = (int*)(keys + (size_t)b * NN);

    uint64_t myk[4]; bool fa[4], fb[4];
    int asum = 0, bsum = 0;
    for (int k = 0; k < 4; ++k) {
        uint64_t key = kb[4 * tid + k]; myk[k] = key;
        unsigned hi = (unsigned)(key >> 32);
        fa[k] = (hi == 0x3F800000u);
        fb[k] = (__uint_as_float(hi) > CONF_T) && !fa[k];
        asum += fa[k] ? 1 : 0; bsum += fb[k] ? 1 : 0;
    }
    int ia = asum, ib = bsum;
    for (int off = 1; off < 64; off <<= 1) {
        int va = __shfl_up(ia, off), vb = __shfl_up(ib, off);
        if (lane >= off) { ia += va; ib += vb; }
    }
    if (lane == 63) { wsumA[wv] = ia; wsumB[wv] = ib; }
    __syncthreads();
    int baseA = 0, baseB = 0, cntA = 0, cntB = 0;
    for (int w2 = 0; w2 < 16; ++w2) {
        if (w2 < wv) { baseA += wsumA[w2]; baseB += wsumB[w2]; }
        cntA += wsumA[w2]; cntB += wsumB[w2];
    }
    int pA = baseA + (ia - asum);
    int pB = baseB + (ib - bsum);
    for (int k = 0; k < 4; ++k) {
        if (fa[k]) og[pA++] = 4 * tid + k;
        if (fb[k]) { if (pB < FBCAP) bbuf[pB] = myk[k]; pB++; }
    }
    int cntBc = cntB < FBCAP ? cntB : FBCAP;
    int nlist = cntA + cntBc;
    if (tid == 0) { keptcnt_s = 0; seg_s = 0; }
    for (int i = tid; i < FBCAP; i += 1024) if (i >= cntB) bbuf[i] = 0;
    __syncthreads();

    for (unsigned k2 = 2; k2 <= FBCAP; k2 <<= 1) {
        for (unsigned j = k2 >> 1; j > 0; j >>= 1) {
            for (unsigned i = tid; i < FBCAP; i += 1024) {
                unsigned p = i ^ j;
                if (p > i) {
                    uint64_t va = bbuf[i], vb = bbuf[p];
                    bool desc = ((i & k2) == 0);
                    if (desc ? (va < vb) : (va > vb)) { bbuf[i] = vb; bbuf[p] = va; }
                }
            }
            __syncthreads();
        }
    }
    for (int i = tid; i < cntBc; i += 1024)
        og[cntA + i] = (int)(0xFFFFFFFFu - (unsigned)(bbuf[i] & 0xFFFFFFFFull));
    if (tid < NWORDS) {
        int lo = tid * 64;
        uint64_t mm;
        if (nlist <= lo) mm = ~0ull;
        else if (nlist >= lo + 64) mm = 0ull;
        else mm = (~0ull) << (nlist - lo);
        sup[tid] = mm;
    }
    __syncthreads();

    for (int i = tid; i < SEGSZ; i += 1024) {
        if (i < nlist) {
            int o = og[i];
            soidx[i] = o;
            const float* bp = bxp + (size_t)o * 4;
            float b0 = bp[0], b1 = bp[1], b2 = bp[2], b3 = bp[3];
            sy1[i] = fminf(b0, b2); sy2[i] = fmaxf(b0, b2);
            sx1[i] = fminf(b1, b3); sx2[i] = fmaxf(b1, b3);
        }
    }
    __syncthreads();

    int curw = 0, segr = 0;
    while (true) {
        if (tid == 0) {
            int code = -1;
            for (;;) {
                int wend = (segr + 1) * (SEGSZ / 64);
                if (curw >= wend) {
                    if (segr == 0 && nlist > SEGSZ) {
                        code = -2; segr = 1; seg_s = 1; curw = SEGSZ / 64;
                    } else code = -1;
                    break;
                }
                uint64_t live = ~sup[curw];
                if (live) {
                    int j = __ffsll((unsigned long long)live) - 1;
                    int sel = curw * 64 + j;
                    int li = sel - segr * SEGSZ;
                    int kc = keptcnt_s;
                    keptidx[kc] = soidx[li];
                    ky1[kc] = sy1[li]; kx1[kc] = sx1[li];
                    ky2[kc] = sy2[li]; kx2[kc] = sx2[li];
                    kar[kc] = (sy2[li] - sy1[li]) * (sx2[li] - sx1[li]);
                    keptcnt_s = kc + 1;
                    sup[curw] |= (1ull << j);
                    code = (kc + 1 >= MAXD) ? -1 : sel;
                    break;
                }
                ++curw;
            }
            ctrl_s = code;
        }
        __syncthreads();
        int c = ctrl_s;
        if (c == -1) break;

        if (c == -2) {
            for (int i = tid; i < SEGSZ; i += 1024) {
                int gi = SEGSZ + i;
                if (gi < nlist) {
                    int o = og[gi];
                    soidx[i] = o;
                    const float* bp = bxp + (size_t)o * 4;
                    float b0 = bp[0], b1 = bp[1], b2 = bp[2], b3 = bp[3];
                    sy1[i] = fminf(b0, b2); sy2[i] = fmaxf(b0, b2);
                    sx1[i] = fminf(b1, b3); sx2[i] = fmaxf(b1, b3);
                }
            }
            __syncthreads();
            int kc = keptcnt_s;
            for (int k = 0; k < 2; ++k) {
                int li = tid + k * 1024;
                float y1 = sy1[li], y2 = sy2[li], x1 = sx1[li], x2 = sx2[li];
                float ar = (y2 - y1) * (x2 - x1);
                bool s = false;
                for (int q = 0; q < kc; ++q) {
                    float ih = fmaxf(0.f, fminf(y2, ky2[q]) - fmaxf(y1, ky1[q]));
                    float iw = fmaxf(0.f, fminf(x2, kx2[q]) - fmaxf(x1, kx1[q]));
                    float inter = ih * iw;
                    float uni = (ar + kar[q]) - inter;
                    s = s || (inter > 0.f && inter / uni > 0.5f);
                }
                uint64_t bal = __ballot(s);
                if (lane == 0 && bal) {
                    int word = (SEGSZ + k * 1024 + wv * 64) >> 6;
                    sup[word] |= bal;
                }
            }
            __syncthreads();
            continue;
        }

        int sg = seg_s;
        int cl = c - sg * SEGSZ;
        float cy1 = sy1[cl], cy2 = sy2[cl], cx1 = sx1[cl], cx2 = sx2[cl];
        float car = (cy2 - cy1) * (cx2 - cx1);
        for (int k = 0; k < 2; ++k) {
            int li = tid + k * 1024;
            float y1 = sy1[li], y2 = sy2[li], x1 = sx1[li], x2 = sx2[li];
            float ar = (y2 - y1) * (x2 - x1);
            float ih = fmaxf(0.f, fminf(y2, cy2) - fmaxf(y1, cy1));
            float iw = fmaxf(0.f, fminf(x2, cx2) - fmaxf(x1, cx1));
            float inter = ih * iw;
            float uni = (ar + car) - inter;
            bool s = (inter > 0.f) && (inter / uni > 0.5f);
            uint64_t bal = __ballot(s);
            if (lane == 0 && bal) {
                int word = (sg * SEGSZ + k * 1024 + wv * 64) >> 6;
                sup[word] |= bal;
            }
        }
        __syncthreads();
    }

    if (tid == 0) cnt_out[b] = keptcnt_s;
    for (int i = tid; i < MAXD; i += 1024)
        kidx_out[b * MAXD + i] = (i < keptcnt_s) ? keptidx[i] : 0;
}

extern "C" void kernel_launch(void* const* d_in, const int* in_sizes, int n_in,
                              void* d_out, int out_size, void* d_ws, size_t ws_size,
                              hipStream_t stream) {
    const float* boxes = (const float*)d_in[0];   // [B,N,4]
    const float* cls   = (const float*)d_in[1];   // [B,N,C]
    float* out = (float*)d_out;
    float* out_box = out;                                                  // [B,100,4]
    float* out_cls = out + (size_t)BB * MAXD * 4;                          // [B,100,80]
    float* probs   = out + (size_t)BB * MAXD * 4 + (size_t)BB * MAXD * CC; // [B,N,80]

    char* ws = (char*)d_ws;
    uint64_t* keys = (uint64_t*)(ws + WS_KEYS);

    if (ws_size >= (size_t)WS_NEED) {
        int* cnt = (int*)(ws + WS_CNT);
        hipMemsetAsync(cnt, 0, BB * sizeof(int), stream);
        k_fused<<<NMSB + NPROD, 1024, 0, stream>>>(boxes, cls, probs, keys, cnt,
                                                   out_box, out_cls);
    } else {
        k_softmax<<<(BB * NN * 8) / 256, 256, 0, stream>>>(cls, probs, keys);
        int* kidx = (int*)(ws + (size_t)BB * NN * sizeof(uint64_t));
        int* cnt  = kidx + BB * MAXD;
        k_nms_fb<<<BB, 1024, 0, stream>>>(keys, boxes, kidx, cnt);
        k_gather<<<(BB * PER_B + 255) / 256, 256, 0, stream>>>(boxes, probs, kidx, cnt,
                                                               out_box, out_cls);
    }
}

// Round 8
// 106.490 us; speedup vs baseline: 1.0969x; 1.0969x over previous
//
#include <hip/hip_runtime.h>
#include <cstdint>
#include <cstddef>

#define BB 16
#define NN 4096
#define CC 80
#define MAXD 100
#define CONF_T 0.5f
#define PER_B (MAXD * 4 + MAXD * CC)   // 8400 output elems per batch
#define NWORDS 64                      // 4096/64 bitmap words (fallback)
#define FBCAP 2048                     // fallback kernel's capacity
#define SEGSZ 2048
#define TK 128                         // g-block width (2 mask words)

// fl32(inter/uni) > 0.5  <=>  inter > uni*(0.5+2^-25), evaluated EXACTLY in
// fp64 (24-bit x 25-bit mantissa product = 49 bits < 53). Bit-identical to
// the reference's IEEE divide + compare. (verified passing rounds 9)
#define IOUC 0x1.000001p-1

// ---- workspace layout ----
#define WS_KEYS   0x000000             // [B*N] u64
#define WS_NEED   0x200000             // 2 MB

// ---------------------------------------------------------------------------
// K1: softmax of (10x)^2 per row — 8 LANES per row, all-register, no LDS.
// Lane j owns elements {j, j+8, ..., j+72}: exactly the numpy pairwise-8
// groups, so the sequential per-lane accumulation == r8[j] chain bitwise.
// (verified passing rounds 2-7)
// ---------------------------------------------------------------------------
__global__ __launch_bounds__(256) void k_softmax(const float* __restrict__ cls_in,
                                                 float* __restrict__ probs,
                                                 uint64_t* __restrict__ keys) {
#pragma clang fp contract(off)
    int slot = blockIdx.x * 256 + threadIdx.x;   // 8 slots per row
    int row  = slot >> 3;                        // [0, B*N)
    int j    = slot & 7;
    const float* rp = cls_in + (size_t)row * CC + j;

    float e[10];
    float m = -3.402823466e+38f;
    #pragma unroll
    for (int k = 0; k < 10; ++k) {
        float y = rp[8 * k] * 10.0f;
        float z = y * y;
        e[k] = z;
        m = fmaxf(m, z);
    }
    m = fmaxf(m, __shfl_xor(m, 1));
    m = fmaxf(m, __shfl_xor(m, 2));
    m = fmaxf(m, __shfl_xor(m, 4));

    #pragma unroll
    for (int k = 0; k < 10; ++k) e[k] = expf(e[k] - m);

    float acc = e[0];
    #pragma unroll
    for (int k = 1; k < 10; ++k) acc += e[k];    // r8[j] sequential chain
    acc = acc + __shfl_xor(acc, 1);              // (r0+r1) ...
    acc = acc + __shfl_xor(acc, 2);              // (r0+r1)+(r2+r3) ...
    acc = acc + __shfl_xor(acc, 4);              // full pairwise tree

    float score = 1.0f / acc;
    float* pp = probs + (size_t)row * CC + j;
    #pragma unroll
    for (int k = 0; k < 10; ++k) pp[8 * k] = e[k] * score;

    if (j == 0) {
        unsigned n = (unsigned)(row & (NN - 1));
        keys[row] = ((uint64_t)__float_as_uint(score) << 32)
                  | (uint64_t)(0xFFFFFFFFu - n);
    }
}

// ---------------------------------------------------------------------------
// K2: partition + rank-sort + sorted-corner LDS build + 128-wide 2-barrier
// block-sequential NMS + fused output gather. One block (16 waves)/batch.
//
// Per 128-wide g-block (vs r4's 64-wide, 3-barrier):
//   [phase1: each lane's 2 candidates vs keeps-so-far, keeps strided across
//    the 16 waves -> persup[wv][2]  ||  phase2: 128x128 kill matrix, 8 rows
//    per wave, lane's candidate corners reused from registers]   (no sync
//    between them: disjoint LDS writes)
//   -> ONE barrier ->
//   wave0: fold sup words, 128-step prefetched exact greedy replay over 2
//   mask words, append keeps (ascending position) + stage corners
//   -> loop-top barrier publishes.
// 2 barriers/block, ~11 live blocks. Greedy sequence identical to r4/r6
// (verified): pre-suppression = kills by earlier keeps; replay ascending;
// same fp64 IOUC compare everywhere.
// ---------------------------------------------------------------------------
__global__ __launch_bounds__(1024) void k_pnms(const uint64_t* __restrict__ keys,
                                               const float* __restrict__ boxes,
                                               const float* __restrict__ probs,
                                               float* __restrict__ out_box,
                                               float* __restrict__ out_cls) {
#pragma clang fp contract(off)
    __shared__ __align__(16) unsigned char sraw[6 * NN * 4];   // 96 KB
    float* hy1 = (float*)sraw;
    float* hx1 = (float*)(sraw + NN * 4);
    float* hy2 = (float*)(sraw + 2 * NN * 4);
    float* hx2 = (float*)(sraw + 3 * NN * 4);
    float* har = (float*)(sraw + 4 * NN * 4);
    int*   og  = (int*)(sraw + 5 * NN * 4);
    uint64_t* bbuf = (uint64_t*)sraw;          // overlays hy1+hx1 (32 KB); dead after sort
    __shared__ uint64_t kill[TK][2];           // 2 KB: row t kills cols [w*64+lane]
    __shared__ uint64_t persup[16][2];
    __shared__ float ky1[MAXD], kx1[MAXD], ky2[MAXD], kx2[MAXD], kar[MAXD]; // staged keeps
    __shared__ int kpos[MAXD];                 // sorted positions of keeps
    __shared__ int fidx[MAXD];
    __shared__ int wsumA[16], wsumB[16];
    __shared__ int kept_s, done_s;

    const int tid = threadIdx.x, lane = tid & 63, wv = tid >> 6;
    const int b = blockIdx.x;
    const uint64_t* kb = keys + (size_t)b * NN;
    const float* bxp = boxes + (size_t)b * NN * 4;

    // ---- partition (og/bbuf in LDS, keys untouched; verbatim) ----
    uint64_t myk[4]; bool fa[4], fb[4];
    int asum = 0, bsum = 0;
    for (int k = 0; k < 4; ++k) {
        uint64_t key = kb[4 * tid + k]; myk[k] = key;
        unsigned hi = (unsigned)(key >> 32);
        fa[k] = (hi == 0x3F800000u);
        fb[k] = (__uint_as_float(hi) > CONF_T) && !fa[k];
        asum += fa[k] ? 1 : 0; bsum += fb[k] ? 1 : 0;
    }
    int ia = asum, ib = bsum;                       // wave-inclusive scans
    for (int off = 1; off < 64; off <<= 1) {
        int va = __shfl_up(ia, off), vb = __shfl_up(ib, off);
        if (lane >= off) { ia += va; ib += vb; }
    }
    if (lane == 63) { wsumA[wv] = ia; wsumB[wv] = ib; }
    __syncthreads();
    int baseA = 0, baseB = 0, cntA = 0, cntB = 0;
    for (int w2 = 0; w2 < 16; ++w2) {
        if (w2 < wv) { baseA += wsumA[w2]; baseB += wsumB[w2]; }
        cntA += wsumA[w2]; cntB += wsumB[w2];
    }
    int pA = baseA + (ia - asum);
    int pB = baseB + (ib - bsum);
    for (int k = 0; k < 4; ++k) {
        if (fa[k]) og[pA++] = 4 * tid + k;          // stable: idx order
        if (fb[k]) bbuf[pB++] = myk[k];             // pB < cntB <= 4096 always
    }
    __syncthreads();

    // ---- rank sort of B (descending, keys unique): one barrier ----
    for (int i = tid; i < cntB; i += 1024) {
        uint64_t ki = bbuf[i];
        int rank = 0;
        for (int j = 0; j < cntB; ++j) rank += (bbuf[j] > ki) ? 1 : 0;
        og[cntA + rank] = (int)(0xFFFFFFFFu - (unsigned)(ki & 0xFFFFFFFFull));
    }
    int nl = cntA + cntB; if (nl > NN) nl = NN;
    __syncthreads();   // bbuf reads done; og complete

    // ---- sorted corner build into LDS (overwrites bbuf region) ----
    for (int i = tid; i < nl; i += 1024) {
        int o = og[i];
        float4 bv = ((const float4*)bxp)[o];
        float y1 = fminf(bv.x, bv.z), y2 = fmaxf(bv.x, bv.z);
        float x1 = fminf(bv.y, bv.w), x2 = fmaxf(bv.y, bv.w);
        hy1[i] = y1; hx1[i] = x1; hy2[i] = y2; hx2[i] = x2;
        har[i] = (y2 - y1) * (x2 - x1);
    }
    if (tid == 0) { kept_s = 0; done_s = 0; }

    // ---- 128-wide 2-barrier block-sequential greedy ----
    int ng = (nl + TK - 1) / TK;
    for (int g = 0; g < ng; ++g) {
        __syncthreads();                           // B_top: publish keeps/done; kill safe
        if (done_s) break;                         // uniform
        int kt = kept_s;                           // uniform; < MAXD here (else done)
        int i0 = g * TK + lane;
        int i1 = i0 + 64;
        bool v0 = i0 < nl, v1 = i1 < nl;
        int ii0 = v0 ? i0 : 0, ii1 = v1 ? i1 : 0;
        float a_y1 = hy1[ii0], a_x1 = hx1[ii0], a_y2 = hy2[ii0], a_x2 = hx2[ii0], a_ar = har[ii0];
        float b_y1 = hy1[ii1], b_x1 = hx1[ii1], b_y2 = hy2[ii1], b_x2 = hx2[ii1], b_ar = har[ii1];

        // -- phase 1: pre-filter both candidates vs keeps, strided across waves --
        bool k0f = false, k1f = false;
        for (int q = wv; q < kt; q += 16) {        // wave-uniform broadcast reads
            float qy1 = ky1[q], qx1 = kx1[q], qy2 = ky2[q], qx2 = kx2[q], qar = kar[q];
            float ih0 = fmaxf(0.f, fminf(a_y2, qy2) - fmaxf(a_y1, qy1));
            float iw0 = fmaxf(0.f, fminf(a_x2, qx2) - fmaxf(a_x1, qx1));
            float in0 = ih0 * iw0;
            float un0 = (a_ar + qar) - in0;
            k0f = k0f || (in0 > 0.f && (double)in0 > (double)un0 * IOUC);
            float ih1 = fmaxf(0.f, fminf(b_y2, qy2) - fmaxf(b_y1, qy1));
            float iw1 = fmaxf(0.f, fminf(b_x2, qx2) - fmaxf(b_x1, qx1));
            float in1 = ih1 * iw1;
            float un1 = (b_ar + qar) - in1;
            k1f = k1f || (in1 > 0.f && (double)in1 > (double)un1 * IOUC);
        }
        uint64_t pw0 = __ballot((!v0) || k0f);
        uint64_t pw1 = __ballot((!v1) || k1f);
        if (lane == 0) { persup[wv][0] = pw0; persup[wv][1] = pw1; }

        // -- phase 2 (same span, no sync needed): 128x128 kill matrix,
        //    8 rows per wave; candidate corners reused from registers --
        #pragma unroll
        for (int r = 0; r < 8; ++r) {
            int t = wv * 8 + r;                    // wave-uniform row in [0,128)
            int it = g * TK + t;
            bool tv = it < nl;
            int itx = tv ? it : 0;
            float ty1 = hy1[itx], tx1 = hx1[itx], ty2 = hy2[itx], tx2 = hx2[itx], tar = har[itx];
            float ih0 = fmaxf(0.f, fminf(ty2, a_y2) - fmaxf(ty1, a_y1));
            float iw0 = fmaxf(0.f, fminf(tx2, a_x2) - fmaxf(tx1, a_x1));
            float in0 = ih0 * iw0;
            float un0 = (tar + a_ar) - in0;
            bool s0 = tv && v0 && (in0 > 0.f) && ((double)in0 > (double)un0 * IOUC);
            float ih1 = fmaxf(0.f, fminf(ty2, b_y2) - fmaxf(ty1, b_y1));
            float iw1 = fmaxf(0.f, fminf(tx2, b_x2) - fmaxf(tx1, b_x1));
            float in1 = ih1 * iw1;
            float un1 = (tar + b_ar) - in1;
            bool s1 = tv && v1 && (in1 > 0.f) && ((double)in1 > (double)un1 * IOUC);
            uint64_t w0 = __ballot(s0);
            uint64_t w1 = __ballot(s1);
            if (lane == 0) { kill[t][0] = w0; kill[t][1] = w1; }
        }
        __syncthreads();                           // B_mid: persup + kill ready

        // -- wave0: fold + 128-step prefetched exact greedy replay --
        if (wv == 0) {
            uint64_t sup0 = 0, sup1 = 0;
            #pragma unroll
            for (int w2 = 0; w2 < 16; ++w2) { sup0 |= persup[w2][0]; sup1 |= persup[w2][1]; }
            uint64_t m0 = 0, m1 = 0;
            #pragma unroll
            for (int c8 = 0; c8 < 8; ++c8) {
                uint64_t kk0[8], kk1[8];
                #pragma unroll
                for (int u = 0; u < 8; ++u) { kk0[u] = kill[c8 * 8 + u][0]; kk1[u] = kill[c8 * 8 + u][1]; }
                #pragma unroll
                for (int u = 0; u < 8; ++u) {
                    int t = c8 * 8 + u;
                    if (!((sup0 >> t) & 1ull)) { m0 |= 1ull << t; sup0 |= kk0[u]; sup1 |= kk1[u]; }
                }
            }
            #pragma unroll
            for (int c8 = 0; c8 < 8; ++c8) {
                uint64_t kk0[8], kk1[8];
                #pragma unroll
                for (int u = 0; u < 8; ++u) { kk0[u] = kill[64 + c8 * 8 + u][0]; kk1[u] = kill[64 + c8 * 8 + u][1]; }
                #pragma unroll
                for (int u = 0; u < 8; ++u) {
                    int t = c8 * 8 + u;
                    if (!((sup1 >> t) & 1ull)) { m1 |= 1ull << t; sup0 |= kk0[u]; sup1 |= kk1[u]; }
                }
            }
            int k0 = kept_s;
            int c0 = __popcll(m0), c1 = __popcll(m1);
            uint64_t below = (1ull << lane) - 1ull;
            if ((m0 >> lane) & 1ull) {
                int pos = k0 + __popcll(m0 & below);
                if (pos < MAXD) {
                    int i = g * TK + lane;
                    kpos[pos] = i;
                    ky1[pos] = hy1[i]; kx1[pos] = hx1[i];
                    ky2[pos] = hy2[i]; kx2[pos] = hx2[i]; kar[pos] = har[i];
                }
            }
            if ((m1 >> lane) & 1ull) {
                int pos = k0 + c0 + __popcll(m1 & below);
                if (pos < MAXD) {
                    int i = g * TK + 64 + lane;
                    kpos[pos] = i;
                    ky1[pos] = hy1[i]; kx1[pos] = hx1[i];
                    ky2[pos] = hy2[i]; kx2[pos] = hx2[i]; kar[pos] = har[i];
                }
            }
            if (lane == 0) {
                int k1 = k0 + c0 + c1;
                kept_s = k1;
                done_s = (k1 >= MAXD) ? 1 : 0;
            }
        }
        // loop-top barrier publishes wave0's writes
    }
    __syncthreads();                               // publish kept_s/kpos (exit paths)

    // ---- fused output gather (exact k_gather semantics) ----
    int kt = kept_s; if (kt > MAXD) kt = MAXD;
    if (tid < MAXD) fidx[tid] = (tid < kt) ? og[kpos[tid]] : 0;
    __syncthreads();

    float* ob = out_box + (size_t)b * MAXD * 4;
    float* oc = out_cls + (size_t)b * MAXD * CC;
    const float* pb = probs + (size_t)b * NN * CC;
    for (int r = tid; r < MAXD * 4; r += 1024) {
        int t = r >> 2, e2 = r & 3;
        float val = 0.0f;
        if (t < kt) { int idx = fidx[t]; val = bxp[(size_t)idx * 4 + e2]; }
        ob[r] = val;
    }
    for (int q = tid; q < MAXD * CC; q += 1024) {
        int t = q / CC, c = q - t * CC;
        float val = 0.0f;
        if (t < kt) { int idx = fidx[t]; val = pb[(size_t)idx * CC + c]; }
        oc[q] = val;
    }
}

// ---------------------------------------------------------------------------
// K4: wide parallel gather (fallback path only).
// ---------------------------------------------------------------------------
__global__ __launch_bounds__(256) void k_gather(const float* __restrict__ boxes,
                                                const float* __restrict__ probs,
                                                const int* __restrict__ kidx,
                                                const int* __restrict__ cnt,
                                                float* __restrict__ out_box,
                                                float* __restrict__ out_cls) {
    int u = blockIdx.x * 256 + threadIdx.x;
    if (u >= BB * PER_B) return;
    int b = u / PER_B;
    int r = u - b * PER_B;
    int count = cnt[b];
    float val = 0.0f;
    if (r < MAXD * 4) {
        int t = r >> 2, e = r & 3;
        if (t < count) {
            int idx = kidx[b * MAXD + t];
            val = boxes[((size_t)b * NN + idx) * 4 + e];
        }
        out_box[(size_t)b * MAXD * 4 + r] = val;
    } else {
        int q = r - MAXD * 4;
        int t = q / CC, c = q - t * CC;
        if (t < count) {
            int idx = kidx[b * MAXD + t];
            val = probs[((size_t)b * NN + idx) * CC + c];
        }
        out_cls[(size_t)b * MAXD * CC + q] = val;
    }
}

// ---------------------------------------------------------------------------
// FALLBACK (ws too small): round-4 fused k_nms — verified passing.
// ---------------------------------------------------------------------------
__global__ __launch_bounds__(1024) void k_nms_fb(uint64_t* keys,
                                                 const float* __restrict__ boxes,
                                                 int* __restrict__ kidx_out,
                                                 int* __restrict__ cnt_out) {
#pragma clang fp contract(off)
    __shared__ float sy1[SEGSZ], sx1[SEGSZ], sy2[SEGSZ], sx2[SEGSZ];
    __shared__ int   soidx[SEGSZ];
    __shared__ uint64_t bbuf[FBCAP];
    __shared__ uint64_t sup[NWORDS];
    __shared__ float ky1[MAXD], kx1[MAXD], ky2[MAXD], kx2[MAXD], kar[MAXD];
    __shared__ int   keptidx[MAXD];
    __shared__ int   wsumA[16], wsumB[16];
    __shared__ int   keptcnt_s, ctrl_s, seg_s;

    const int tid = threadIdx.x, lane = tid & 63, wv = tid >> 6;
    const int b = blockIdx.x;
    const uint64_t* kb = keys + (size_t)b * NN;
    const float* bxp = boxes + (size_t)b * NN * 4;
    int* og = (int*)(keys + (size_t)b * NN);

    uint64_t myk[4]; bool fa[4], fb[4];
    int asum = 0, bsum = 0;
    for (int k = 0; k < 4; ++k) {
        uint64_t key = kb[4 * tid + k]; myk[k] = key;
        unsigned hi = (unsigned)(key >> 32);
        fa[k] = (hi == 0x3F800000u);
        fb[k] = (__uint_as_float(hi) > CONF_T) && !fa[k];
        asum += fa[k] ? 1 : 0; bsum += fb[k] ? 1 : 0;
    }
    int ia = asum, ib = bsum;
    for (int off = 1; off < 64; off <<= 1) {
        int va = __shfl_up(ia, off), vb = __shfl_up(ib, off);
        if (lane >= off) { ia += va; ib += vb; }
    }
    if (lane == 63) { wsumA[wv] = ia; wsumB[wv] = ib; }
    __syncthreads();
    int baseA = 0, baseB = 0, cntA = 0, cntB = 0;
    for (int w2 = 0; w2 < 16; ++w2) {
        if (w2 < wv) { baseA += wsumA[w2]; baseB += wsumB[w2]; }
        cntA += wsumA[w2]; cntB += wsumB[w2];
    }
    int pA = baseA + (ia - asum);
    int pB = baseB + (ib - bsum);
    for (int k = 0; k < 4; ++k) {
        if (fa[k]) og[pA++] = 4 * tid + k;
        if (fb[k]) { if (pB < FBCAP) bbuf[pB] = myk[k]; pB++; }
    }
    int cntBc = cntB < FBCAP ? cntB : FBCAP;
    int nlist = cntA + cntBc;
    if (tid == 0) { keptcnt_s = 0; seg_s = 0; }
    for (int i = tid; i < FBCAP; i += 1024) if (i >= cntB) bbuf[i] = 0;
    __syncthreads();

    for (unsigned k2 = 2; k2 <= FBCAP; k2 <<= 1) {
        for (unsigned j = k2 >> 1; j > 0; j >>= 1) {
            for (unsigned i = tid; i < FBCAP; i += 1024) {
                unsigned p = i ^ j;
                if (p > i) {
                    uint64_t va = bbuf[i], vb = bbuf[p];
                    bool desc = ((i & k2) == 0);
                    if (desc ? (va < vb) : (va > vb)) { bbuf[i] = vb; bbuf[p] = va; }
                }
            }
            __syncthreads();
        }
    }
    for (int i = tid; i < cntBc; i += 1024)
        og[cntA + i] = (int)(0xFFFFFFFFu - (unsigned)(bbuf[i] & 0xFFFFFFFFull));
    if (tid < NWORDS) {
        int lo = tid * 64;
        uint64_t mm;
        if (nlist <= lo) mm = ~0ull;
        else if (nlist >= lo + 64) mm = 0ull;
        else mm = (~0ull) << (nlist - lo);
        sup[tid] = mm;
    }
    __syncthreads();

    for (int i = tid; i < SEGSZ; i += 1024) {
        if (i < nlist) {
            int o = og[i];
            soidx[i] = o;
            const float* bp = bxp + (size_t)o * 4;
            float b0 = bp[0], b1 = bp[1], b2 = bp[2], b3 = bp[3];
            sy1[i] = fminf(b0, b2); sy2[i] = fmaxf(b0, b2);
            sx1[i] = fminf(b1, b3); sx2[i] = fmaxf(b1, b3);
        }
    }
    __syncthreads();

    int curw = 0, segr = 0;
    while (true) {
        if (tid == 0) {
            int code = -1;
            for (;;) {
                int wend = (segr + 1) * (SEGSZ / 64);
                if (curw >= wend) {
                    if (segr == 0 && nlist > SEGSZ) {
                        code = -2; segr = 1; seg_s = 1; curw = SEGSZ / 64;
                    } else code = -1;
                    break;
                }
                uint64_t live = ~sup[curw];
                if (live) {
                    int j = __ffsll((unsigned long long)live) - 1;
                    int sel = curw * 64 + j;
                    int li = sel - segr * SEGSZ;
                    int kc = keptcnt_s;
                    keptidx[kc] = soidx[li];
                    ky1[kc] = sy1[li]; kx1[kc] = sx1[li];
                    ky2[kc] = sy2[li]; kx2[kc] = sx2[li];
                    kar[kc] = (sy2[li] - sy1[li]) * (sx2[li] - sx1[li]);
                    keptcnt_s = kc + 1;
                    sup[curw] |= (1ull << j);
                    code = (kc + 1 >= MAXD) ? -1 : sel;
                    break;
                }
                ++curw;
            }
            ctrl_s = code;
        }
        __syncthreads();
        int c = ctrl_s;
        if (c == -1) break;

        if (c == -2) {
            for (int i = tid; i < SEGSZ; i += 1024) {
                int gi = SEGSZ + i;
                if (gi < nlist) {
                    int o = og[gi];
                    soidx[i] = o;
                    const float* bp = bxp + (size_t)o * 4;
                    float b0 = bp[0], b1 = bp[1], b2 = bp[2], b3 = bp[3];
                    sy1[i] = fminf(b0, b2); sy2[i] = fmaxf(b0, b2);
                    sx1[i] = fminf(b1, b3); sx2[i] = fmaxf(b1, b3);
                }
            }
            __syncthreads();
            int kc = keptcnt_s;
            for (int k = 0; k < 2; ++k) {
                int li = tid + k * 1024;
                float y1 = sy1[li], y2 = sy2[li], x1 = sx1[li], x2 = sx2[li];
                float ar = (y2 - y1) * (x2 - x1);
                bool s = false;
                for (int q = 0; q < kc; ++q) {
                    float ih = fmaxf(0.f, fminf(y2, ky2[q]) - fmaxf(y1, ky1[q]));
                    float iw = fmaxf(0.f, fminf(x2, kx2[q]) - fmaxf(x1, kx1[q]));
                    float inter = ih * iw;
                    float uni = (ar + kar[q]) - inter;
                    s = s || (inter > 0.f && inter / uni > 0.5f);
                }
                uint64_t bal = __ballot(s);
                if (lane == 0 && bal) {
                    int word = (SEGSZ + k * 1024 + wv * 64) >> 6;
                    sup[word] |= bal;
                }
            }
            __syncthreads();
            continue;
        }

        int sg = seg_s;
        int cl = c - sg * SEGSZ;
        float cy1 = sy1[cl], cy2 = sy2[cl], cx1 = sx1[cl], cx2 = sx2[cl];
        float car = (cy2 - cy1) * (cx2 - cx1);
        for (int k = 0; k < 2; ++k) {
            int li = tid + k * 1024;
            float y1 = sy1[li], y2 = sy2[li], x1 = sx1[li], x2 = sx2[li];
            float ar = (y2 - y1) * (x2 - x1);
            float ih = fmaxf(0.f, fminf(y2, cy2) - fmaxf(y1, cy1));
            float iw = fmaxf(0.f, fminf(x2, cx2) - fmaxf(x1, cx1));
            float inter = ih * iw;
            float uni = (ar + car) - inter;
            bool s = (inter > 0.f) && (inter / uni > 0.5f);
            uint64_t bal = __ballot(s);
            if (lane == 0 && bal) {
                int word = (sg * SEGSZ + k * 1024 + wv * 64) >> 6;
                sup[word] |= bal;
            }
        }
        __syncthreads();
    }

    if (tid == 0) cnt_out[b] = keptcnt_s;
    for (int i = tid; i < MAXD; i += 1024)
        kidx_out[b * MAXD + i] = (i < keptcnt_s) ? keptidx[i] : 0;
}

extern "C" void kernel_launch(void* const* d_in, const int* in_sizes, int n_in,
                              void* d_out, int out_size, void* d_ws, size_t ws_size,
                              hipStream_t stream) {
    const float* boxes = (const float*)d_in[0];   // [B,N,4]
    const float* cls   = (const float*)d_in[1];   // [B,N,C]
    float* out = (float*)d_out;
    float* out_box = out;                                                  // [B,100,4]
    float* out_cls = out + (size_t)BB * MAXD * 4;                          // [B,100,80]
    float* probs   = out + (size_t)BB * MAXD * 4 + (size_t)BB * MAXD * CC; // [B,N,80]

    char* ws = (char*)d_ws;
    uint64_t* keys = (uint64_t*)(ws + WS_KEYS);

    k_softmax<<<(BB * NN * 8) / 256, 256, 0, stream>>>(cls, probs, keys);

    if (ws_size >= (size_t)WS_NEED) {
        k_pnms<<<BB, 1024, 0, stream>>>(keys, boxes, probs, out_box, out_cls);
    } else {
        int* kidx = (int*)(ws + (size_t)BB * NN * sizeof(uint64_t));
        int* cnt  = kidx + BB * MAXD;
        k_nms_fb<<<BB, 1024, 0, stream>>>(keys, boxes, kidx, cnt);
        k_gather<<<(BB * PER_B + 255) / 256, 256, 0, stream>>>(boxes, probs, kidx, cnt,
                                                               out_box, out_cls);
    }
}

// Round 9
// 100.124 us; speedup vs baseline: 1.1667x; 1.0636x over previous
//
#include <hip/hip_runtime.h>
#include <cstdint>
#include <cstddef>

#define BB 16
#define NN 4096
#define CC 80
#define MAXD 100
#define CONF_T 0.5f
#define PER_B (MAXD * 4 + MAXD * CC)   // 8400 output elems per batch
#define NWORDS 64                      // 4096/64 bitmap words (fallback)
#define FBCAP 2048                     // fallback kernel's capacity
#define SEGSZ 2048

// fl32(inter/uni) > 0.5  <=>  inter > uni*(0.5+2^-25), evaluated EXACTLY in
// fp64 (24-bit x 25-bit mantissa product = 49 bits < 53). Bit-identical to
// the reference's IEEE divide + compare. (verified passing rounds 9)
#define IOUC 0x1.000001p-1

// ---- workspace layout ----
#define WS_KEYS   0x000000             // [B*N] u64
#define WS_NEED   0x200000             // 2 MB

// ---------------------------------------------------------------------------
// K1: softmax of (10x)^2 per row — 8 LANES per row, all-register, no LDS.
// Lane j owns elements {j, j+8, ..., j+72}: exactly the numpy pairwise-8
// groups, so the sequential per-lane accumulation == r8[j] chain bitwise.
// (verified passing rounds 2-8)
// ---------------------------------------------------------------------------
__global__ __launch_bounds__(256) void k_softmax(const float* __restrict__ cls_in,
                                                 float* __restrict__ probs,
                                                 uint64_t* __restrict__ keys) {
#pragma clang fp contract(off)
    int slot = blockIdx.x * 256 + threadIdx.x;   // 8 slots per row
    int row  = slot >> 3;                        // [0, B*N)
    int j    = slot & 7;
    const float* rp = cls_in + (size_t)row * CC + j;

    float e[10];
    float m = -3.402823466e+38f;
    #pragma unroll
    for (int k = 0; k < 10; ++k) {
        float y = rp[8 * k] * 10.0f;
        float z = y * y;
        e[k] = z;
        m = fmaxf(m, z);
    }
    m = fmaxf(m, __shfl_xor(m, 1));
    m = fmaxf(m, __shfl_xor(m, 2));
    m = fmaxf(m, __shfl_xor(m, 4));

    #pragma unroll
    for (int k = 0; k < 10; ++k) e[k] = expf(e[k] - m);

    float acc = e[0];
    #pragma unroll
    for (int k = 1; k < 10; ++k) acc += e[k];    // r8[j] sequential chain
    acc = acc + __shfl_xor(acc, 1);              // (r0+r1) ...
    acc = acc + __shfl_xor(acc, 2);              // (r0+r1)+(r2+r3) ...
    acc = acc + __shfl_xor(acc, 4);              // full pairwise tree

    float score = 1.0f / acc;
    float* pp = probs + (size_t)row * CC + j;
    #pragma unroll
    for (int k = 0; k < 10; ++k) pp[8 * k] = e[k] * score;

    if (j == 0) {
        unsigned n = (unsigned)(row & (NN - 1));
        keys[row] = ((uint64_t)__float_as_uint(score) << 32)
                  | (uint64_t)(0xFFFFFFFFu - n);
    }
}

// ---------------------------------------------------------------------------
// K2: partition + rank-sort + packed-corner LDS build + block-sequential NMS
// (live-row kill matrix + hybrid replay) + fused output gather.
// One block (1024 thr = 16 waves) per batch. r4 structure with:
//  - corners packed as float4 (y1,x1,y2,x2) + area: 2 LDS ops per operand
//  - phase2 computes kill rows ONLY for live t (sup0 known after S1);
//    stale kill[t] for dead t is never read by replay
//  - replay: ffs-guided when popcount(live)<=12 (iterations = live count;
//    identical greedy sequence to ascending scan), else 8x8-prefetch scan
// Exact greedy semantics identical to the verified r4 kernel.
// ---------------------------------------------------------------------------
__global__ __launch_bounds__(1024) void k_pnms(const uint64_t* __restrict__ keys,
                                               const float* __restrict__ boxes,
                                               const float* __restrict__ probs,
                                               float* __restrict__ out_box,
                                               float* __restrict__ out_cls) {
#pragma clang fp contract(off)
    __shared__ __align__(16) float4 cbox[NN];      // 64 KB (y1,x1,y2,x2) sorted order
    __shared__ float car_s[NN];                    // 16 KB areas
    __shared__ int og[NN];                         // 16 KB sorted->raw
    uint64_t* bbuf = (uint64_t*)cbox;              // overlays cbox (32 KB); dead after sort
    __shared__ uint64_t kill[64];
    __shared__ uint64_t persup[16];
    __shared__ __align__(16) float4 kbx[MAXD];     // staged keep corners
    __shared__ float kar[MAXD];                    // staged keep areas
    __shared__ int kpos[MAXD];                     // sorted positions of keeps
    __shared__ int fidx[MAXD];
    __shared__ int wsumA[16], wsumB[16];
    __shared__ int kept_s, done_s;

    const int tid = threadIdx.x, lane = tid & 63, wv = tid >> 6;
    const int b = blockIdx.x;
    const uint64_t* kb = keys + (size_t)b * NN;
    const float* bxp = boxes + (size_t)b * NN * 4;

    // ---- partition (og/bbuf in LDS, keys untouched; verbatim) ----
    uint64_t myk[4]; bool fa[4], fb[4];
    int asum = 0, bsum = 0;
    for (int k = 0; k < 4; ++k) {
        uint64_t key = kb[4 * tid + k]; myk[k] = key;
        unsigned hi = (unsigned)(key >> 32);
        fa[k] = (hi == 0x3F800000u);
        fb[k] = (__uint_as_float(hi) > CONF_T) && !fa[k];
        asum += fa[k] ? 1 : 0; bsum += fb[k] ? 1 : 0;
    }
    int ia = asum, ib = bsum;                       // wave-inclusive scans
    for (int off = 1; off < 64; off <<= 1) {
        int va = __shfl_up(ia, off), vb = __shfl_up(ib, off);
        if (lane >= off) { ia += va; ib += vb; }
    }
    if (lane == 63) { wsumA[wv] = ia; wsumB[wv] = ib; }
    __syncthreads();
    int baseA = 0, baseB = 0, cntA = 0, cntB = 0;
    for (int w2 = 0; w2 < 16; ++w2) {
        if (w2 < wv) { baseA += wsumA[w2]; baseB += wsumB[w2]; }
        cntA += wsumA[w2]; cntB += wsumB[w2];
    }
    int pA = baseA + (ia - asum);
    int pB = baseB + (ib - bsum);
    for (int k = 0; k < 4; ++k) {
        if (fa[k]) og[pA++] = 4 * tid + k;          // stable: idx order
        if (fb[k]) bbuf[pB++] = myk[k];             // pB < cntB <= 4096 always
    }
    __syncthreads();

    // ---- rank sort of B (descending, keys unique): one barrier ----
    for (int i = tid; i < cntB; i += 1024) {
        uint64_t ki = bbuf[i];
        int rank = 0;
        for (int j = 0; j < cntB; ++j) rank += (bbuf[j] > ki) ? 1 : 0;
        og[cntA + rank] = (int)(0xFFFFFFFFu - (unsigned)(ki & 0xFFFFFFFFull));
    }
    int nl = cntA + cntB; if (nl > NN) nl = NN;
    __syncthreads();   // bbuf reads done; og complete

    // ---- sorted packed-corner build into LDS (overwrites bbuf region) ----
    for (int i = tid; i < nl; i += 1024) {
        int o = og[i];
        float4 bv = ((const float4*)bxp)[o];
        float y1 = fminf(bv.x, bv.z), y2 = fmaxf(bv.x, bv.z);
        float x1 = fminf(bv.y, bv.w), x2 = fmaxf(bv.y, bv.w);
        cbox[i] = make_float4(y1, x1, y2, x2);
        car_s[i] = (y2 - y1) * (x2 - x1);
    }
    if (tid == 0) { kept_s = 0; done_s = 0; }

    // ---- block-sequential greedy over 64-wide g-blocks ----
    int ng = (nl + 63) >> 6;
    for (int g = 0; g < ng; ++g) {
        __syncthreads();                           // S0: publish kept/done
        if (done_s) break;                         // uniform
        int kt = kept_s;                           // uniform; < MAXD here (else done)
        int i = g * 64 + lane;
        bool v = i < nl;
        int ii = v ? i : 0;
        float4 cb = cbox[ii];                      // (y1,x1,y2,x2)
        float ar = car_s[ii];

        // -- phase 1: pre-filter vs keeps, strided across waves --
        bool killed = false;
        for (int q = wv; q < kt; q += 16) {        // wave-uniform broadcast reads
            float4 qb = kbx[q]; float qar = kar[q];
            float ih = fmaxf(0.f, fminf(cb.z, qb.z) - fmaxf(cb.x, qb.x));
            float iw = fmaxf(0.f, fminf(cb.w, qb.w) - fmaxf(cb.y, qb.y));
            float inter = ih * iw;
            float uni = (ar + qar) - inter;
            killed = killed || (inter > 0.f && (double)inter > (double)uni * IOUC);
        }
        uint64_t pw = __ballot((!v) || killed);
        if (lane == 0) persup[wv] = pw;
        __syncthreads();                           // S1: persup ready
        uint64_t sup0 = 0;
        #pragma unroll
        for (int w2 = 0; w2 < 16; ++w2) sup0 |= persup[w2];
        if (sup0 == ~0ull) continue;               // uniform: block fully dead

        // -- phase 2: kill rows for LIVE t only (wave-uniform skip) --
        #pragma unroll
        for (int r = 0; r < 4; ++r) {
            int t = wv + 16 * r;
            if ((sup0 >> t) & 1ull) continue;      // dead row: kill[t] never read
            int it = g * 64 + t;                   // live => it < nl (invalids are dead)
            float4 tb = cbox[it]; float tar = car_s[it];   // wave-uniform broadcast
            float ih = fmaxf(0.f, fminf(tb.z, cb.z) - fmaxf(tb.x, cb.x));
            float iw = fmaxf(0.f, fminf(tb.w, cb.w) - fmaxf(tb.y, cb.y));
            float inter = ih * iw;
            float uni = (tar + ar) - inter;
            bool s = v && (inter > 0.f) && ((double)inter > (double)uni * IOUC);
            uint64_t w = __ballot(s);
            if (lane == 0) kill[t] = w;
        }
        __syncthreads();                           // S2: kill ready

        // -- phase 3: exact greedy replay (wave0), hybrid --
        if (wv == 0) {
            uint64_t livew = ~sup0;
            uint64_t keptm = 0;
            if (__popcll(livew) <= 12) {
                // ffs-guided: iterations = number of keeps in this block.
                // Identical to ascending scan: lowest live bit = next keep.
                uint64_t lv = livew;
                while (lv) {
                    int t = __ffsll((unsigned long long)lv) - 1;
                    keptm |= 1ull << t;
                    uint64_t kk = kill[t];
                    lv &= ~kk;
                    lv &= ~(1ull << t);
                }
            } else {
                uint64_t sup = sup0;
                #pragma unroll
                for (int c8 = 0; c8 < 8; ++c8) {
                    uint64_t kk[8];
                    #pragma unroll
                    for (int u = 0; u < 8; ++u) kk[u] = kill[c8 * 8 + u];  // indep loads
                    #pragma unroll
                    for (int u = 0; u < 8; ++u) {
                        int t = c8 * 8 + u;
                        if (!((sup >> t) & 1ull)) { keptm |= 1ull << t; sup |= kk[u]; }
                    }
                }
            }
            int k0 = kept_s;
            if ((keptm >> lane) & 1ull) {
                int pos = k0 + __popcll(keptm & ((1ull << lane) - 1ull));
                if (pos < MAXD) {
                    kpos[pos] = i;                 // sorted position
                    kbx[pos] = cb;                 // lane-local registers
                    kar[pos] = ar;
                }
            }
            if (lane == 0) {
                int k1 = k0 + __popcll(keptm);
                kept_s = k1;
                done_s = (k1 >= MAXD) ? 1 : 0;
            }
        }
        // next iteration's S0 (or the final barrier) publishes wave0's writes
    }
    __syncthreads();                               // publish kept_s/kpos (exit paths)

    // ---- fused output gather (exact k_gather semantics) ----
    int kt = kept_s; if (kt > MAXD) kt = MAXD;
    if (tid < MAXD) fidx[tid] = (tid < kt) ? og[kpos[tid]] : 0;
    __syncthreads();

    float* ob = out_box + (size_t)b * MAXD * 4;
    float* oc = out_cls + (size_t)b * MAXD * CC;
    const float* pb = probs + (size_t)b * NN * CC;
    for (int r = tid; r < MAXD * 4; r += 1024) {
        int t = r >> 2, e2 = r & 3;
        float val = 0.0f;
        if (t < kt) { int idx = fidx[t]; val = bxp[(size_t)idx * 4 + e2]; }
        ob[r] = val;
    }
    for (int q = tid; q < MAXD * CC; q += 1024) {
        int t = q / CC, c = q - t * CC;
        float val = 0.0f;
        if (t < kt) { int idx = fidx[t]; val = pb[(size_t)idx * CC + c]; }
        oc[q] = val;
    }
}

// ---------------------------------------------------------------------------
// K4: wide parallel gather (fallback path only).
// ---------------------------------------------------------------------------
__global__ __launch_bounds__(256) void k_gather(const float* __restrict__ boxes,
                                                const float* __restrict__ probs,
                                                const int* __restrict__ kidx,
                                                const int* __restrict__ cnt,
                                                float* __restrict__ out_box,
                                                float* __restrict__ out_cls) {
    int u = blockIdx.x * 256 + threadIdx.x;
    if (u >= BB * PER_B) return;
    int b = u / PER_B;
    int r = u - b * PER_B;
    int count = cnt[b];
    float val = 0.0f;
    if (r < MAXD * 4) {
        int t = r >> 2, e = r & 3;
        if (t < count) {
            int idx = kidx[b * MAXD + t];
            val = boxes[((size_t)b * NN + idx) * 4 + e];
        }
        out_box[(size_t)b * MAXD * 4 + r] = val;
    } else {
        int q = r - MAXD * 4;
        int t = q / CC, c = q - t * CC;
        if (t < count) {
            int idx = kidx[b * MAXD + t];
            val = probs[((size_t)b * NN + idx) * CC + c];
        }
        out_cls[(size_t)b * MAXD * CC + q] = val;
    }
}

// ---------------------------------------------------------------------------
// FALLBACK (ws too small): round-4 fused k_nms — verified passing.
// ---------------------------------------------------------------------------
__global__ __launch_bounds__(1024) void k_nms_fb(uint64_t* keys,
                                                 const float* __restrict__ boxes,
                                                 int* __restrict__ kidx_out,
                                                 int* __restrict__ cnt_out) {
#pragma clang fp contract(off)
    __shared__ float sy1[SEGSZ], sx1[SEGSZ], sy2[SEGSZ], sx2[SEGSZ];
    __shared__ int   soidx[SEGSZ];
    __shared__ uint64_t bbuf[FBCAP];
    __shared__ uint64_t sup[NWORDS];
    __shared__ float ky1[MAXD], kx1[MAXD], ky2[MAXD], kx2[MAXD], kar[MAXD];
    __shared__ int   keptidx[MAXD];
    __shared__ int   wsumA[16], wsumB[16];
    __shared__ int   keptcnt_s, ctrl_s, seg_s;

    const int tid = threadIdx.x, lane = tid & 63, wv = tid >> 6;
    const int b = blockIdx.x;
    const uint64_t* kb = keys + (size_t)b * NN;
    const float* bxp = boxes + (size_t)b * NN * 4;
    int* og = (int*)(keys + (size_t)b * NN);

    uint64_t myk[4]; bool fa[4], fb[4];
    int asum = 0, bsum = 0;
    for (int k = 0; k < 4; ++k) {
        uint64_t key = kb[4 * tid + k]; myk[k] = key;
        unsigned hi = (unsigned)(key >> 32);
        fa[k] = (hi == 0x3F800000u);
        fb[k] = (__uint_as_float(hi) > CONF_T) && !fa[k];
        asum += fa[k] ? 1 : 0; bsum += fb[k] ? 1 : 0;
    }
    int ia = asum, ib = bsum;
    for (int off = 1; off < 64; off <<= 1) {
        int va = __shfl_up(ia, off), vb = __shfl_up(ib, off);
        if (lane >= off) { ia += va; ib += vb; }
    }
    if (lane == 63) { wsumA[wv] = ia; wsumB[wv] = ib; }
    __syncthreads();
    int baseA = 0, baseB = 0, cntA = 0, cntB = 0;
    for (int w2 = 0; w2 < 16; ++w2) {
        if (w2 < wv) { baseA += wsumA[w2]; baseB += wsumB[w2]; }
        cntA += wsumA[w2]; cntB += wsumB[w2];
    }
    int pA = baseA + (ia - asum);
    int pB = baseB + (ib - bsum);
    for (int k = 0; k < 4; ++k) {
        if (fa[k]) og[pA++] = 4 * tid + k;
        if (fb[k]) { if (pB < FBCAP) bbuf[pB] = myk[k]; pB++; }
    }
    int cntBc = cntB < FBCAP ? cntB : FBCAP;
    int nlist = cntA + cntBc;
    if (tid == 0) { keptcnt_s = 0; seg_s = 0; }
    for (int i = tid; i < FBCAP; i += 1024) if (i >= cntB) bbuf[i] = 0;
    __syncthreads();

    for (unsigned k2 = 2; k2 <= FBCAP; k2 <<= 1) {
        for (unsigned j = k2 >> 1; j > 0; j >>= 1) {
            for (unsigned i = tid; i < FBCAP; i += 1024) {
                unsigned p = i ^ j;
                if (p > i) {
                    uint64_t va = bbuf[i], vb = bbuf[p];
                    bool desc = ((i & k2) == 0);
                    if (desc ? (va < vb) : (va > vb)) { bbuf[i] = vb; bbuf[p] = va; }
                }
            }
            __syncthreads();
        }
    }
    for (int i = tid; i < cntBc; i += 1024)
        og[cntA + i] = (int)(0xFFFFFFFFu - (unsigned)(bbuf[i] & 0xFFFFFFFFull));
    if (tid < NWORDS) {
        int lo = tid * 64;
        uint64_t mm;
        if (nlist <= lo) mm = ~0ull;
        else if (nlist >= lo + 64) mm = 0ull;
        else mm = (~0ull) << (nlist - lo);
        sup[tid] = mm;
    }
    __syncthreads();

    for (int i = tid; i < SEGSZ; i += 1024) {
        if (i < nlist) {
            int o = og[i];
            soidx[i] = o;
            const float* bp = bxp + (size_t)o * 4;
            float b0 = bp[0], b1 = bp[1], b2 = bp[2], b3 = bp[3];
            sy1[i] = fminf(b0, b2); sy2[i] = fmaxf(b0, b2);
            sx1[i] = fminf(b1, b3); sx2[i] = fmaxf(b1, b3);
        }
    }
    __syncthreads();

    int curw = 0, segr = 0;
    while (true) {
        if (tid == 0) {
            int code = -1;
            for (;;) {
                int wend = (segr + 1) * (SEGSZ / 64);
                if (curw >= wend) {
                    if (segr == 0 && nlist > SEGSZ) {
                        code = -2; segr = 1; seg_s = 1; curw = SEGSZ / 64;
                    } else code = -1;
                    break;
                }
                uint64_t live = ~sup[curw];
                if (live) {
                    int j = __ffsll((unsigned long long)live) - 1;
                    int sel = curw * 64 + j;
                    int li = sel - segr * SEGSZ;
                    int kc = keptcnt_s;
                    keptidx[kc] = soidx[li];
                    ky1[kc] = sy1[li]; kx1[kc] = sx1[li];
                    ky2[kc] = sy2[li]; kx2[kc] = sx2[li];
                    kar[kc] = (sy2[li] - sy1[li]) * (sx2[li] - sx1[li]);
                    keptcnt_s = kc + 1;
                    sup[curw] |= (1ull << j);
                    code = (kc + 1 >= MAXD) ? -1 : sel;
                    break;
                }
                ++curw;
            }
            ctrl_s = code;
        }
        __syncthreads();
        int c = ctrl_s;
        if (c == -1) break;

        if (c == -2) {
            for (int i = tid; i < SEGSZ; i += 1024) {
                int gi = SEGSZ + i;
                if (gi < nlist) {
                    int o = og[gi];
                    soidx[i] = o;
                    const float* bp = bxp + (size_t)o * 4;
                    float b0 = bp[0], b1 = bp[1], b2 = bp[2], b3 = bp[3];
                    sy1[i] = fminf(b0, b2); sy2[i] = fmaxf(b0, b2);
                    sx1[i] = fminf(b1, b3); sx2[i] = fmaxf(b1, b3);
                }
            }
            __syncthreads();
            int kc = keptcnt_s;
            for (int k = 0; k < 2; ++k) {
                int li = tid + k * 1024;
                float y1 = sy1[li], y2 = sy2[li], x1 = sx1[li], x2 = sx2[li];
                float ar = (y2 - y1) * (x2 - x1);
                bool s = false;
                for (int q = 0; q < kc; ++q) {
                    float ih = fmaxf(0.f, fminf(y2, ky2[q]) - fmaxf(y1, ky1[q]));
                    float iw = fmaxf(0.f, fminf(x2, kx2[q]) - fmaxf(x1, kx1[q]));
                    float inter = ih * iw;
                    float uni = (ar + kar[q]) - inter;
                    s = s || (inter > 0.f && inter / uni > 0.5f);
                }
                uint64_t bal = __ballot(s);
                if (lane == 0 && bal) {
                    int word = (SEGSZ + k * 1024 + wv * 64) >> 6;
                    sup[word] |= bal;
                }
            }
            __syncthreads();
            continue;
        }

        int sg = seg_s;
        int cl = c - sg * SEGSZ;
        float cy1 = sy1[cl], cy2 = sy2[cl], cx1 = sx1[cl], cx2 = sx2[cl];
        float car = (cy2 - cy1) * (cx2 - cx1);
        for (int k = 0; k < 2; ++k) {
            int li = tid + k * 1024;
            float y1 = sy1[li], y2 = sy2[li], x1 = sx1[li], x2 = sx2[li];
            float ar = (y2 - y1) * (x2 - x1);
            float ih = fmaxf(0.f, fminf(y2, cy2) - fmaxf(y1, cy1));
            float iw = fmaxf(0.f, fminf(x2, cx2) - fmaxf(x1, cx1));
            float inter = ih * iw;
            float uni = (ar + car) - inter;
            bool s = (inter > 0.f) && (inter / uni > 0.5f);
            uint64_t bal = __ballot(s);
            if (lane == 0 && bal) {
                int word = (sg * SEGSZ + k * 1024 + wv * 64) >> 6;
                sup[word] |= bal;
            }
        }
        __syncthreads();
    }

    if (tid == 0) cnt_out[b] = keptcnt_s;
    for (int i = tid; i < MAXD; i += 1024)
        kidx_out[b * MAXD + i] = (i < keptcnt_s) ? keptidx[i] : 0;
}

extern "C" void kernel_launch(void* const* d_in, const int* in_sizes, int n_in,
                              void* d_out, int out_size, void* d_ws, size_t ws_size,
                              hipStream_t stream) {
    const float* boxes = (const float*)d_in[0];   // [B,N,4]
    const float* cls   = (const float*)d_in[1];   // [B,N,C]
    float* out = (float*)d_out;
    float* out_box = out;                                                  // [B,100,4]
    float* out_cls = out + (size_t)BB * MAXD * 4;                          // [B,100,80]
    float* probs   = out + (size_t)BB * MAXD * 4 + (size_t)BB * MAXD * CC; // [B,N,80]

    char* ws = (char*)d_ws;
    uint64_t* keys = (uint64_t*)(ws + WS_KEYS);

    k_softmax<<<(BB * NN * 8) / 256, 256, 0, stream>>>(cls, probs, keys);

    if (ws_size >= (size_t)WS_NEED) {
        k_pnms<<<BB, 1024, 0, stream>>>(keys, boxes, probs, out_box, out_cls);
    } else {
        int* kidx = (int*)(ws + (size_t)BB * NN * sizeof(uint64_t));
        int* cnt  = kidx + BB * MAXD;
        k_nms_fb<<<BB, 1024, 0, stream>>>(keys, boxes, kidx, cnt);
        k_gather<<<(BB * PER_B + 255) / 256, 256, 0, stream>>>(boxes, probs, kidx, cnt,
                                                               out_box, out_cls);
    }
}